// Round 3
// baseline (360.190 us; speedup 1.0000x reference)
//
#include <hip/hip_runtime.h>

// GlobalQuantizedLatent: per-element nearest-codebook quantization.
// N = 16,777,216 f32, V = 16 codebook entries (linspace(-0.5, 0.5, 16)).
// Outputs (concatenated flat, all read back as f32 by the harness):
//   [0,   N) : x            (copy of input)
//   [N,  2N) : quantized    (values[argmin |x - values|])
//   [2N, 3N) : z_hat        (== quantized numerically in forward)
//   [3N, 4N) : indices      (argmin index, stored as float)
//
// Memory-bound: 64 MiB read + 256 MiB write => ~53 us floor at 6.3 TB/s.
// R2: nontemporal builtins need native clang vectors, not HIP_vector_type
// (R1 compile error) — use ext_vector_type(4) float.
//
// NOTE: the argmin MUST be the exact first-wins distance-compare loop.
// A closed-form round((x+0.5)*15) disagrees with f32 distance comparison
// for x within ~1 ulp of codebook midpoints (~a few of 16.7M elements),
// giving index error 1.0 > the 0.3 threshold.

#define BLOCK 256
#define NVALS 16
#define EPT 8  // elements per thread

typedef float v4f __attribute__((ext_vector_type(4)));

__global__ __launch_bounds__(BLOCK) void
GlobalQuantizedLatent_87900800680047_kernel(const float* __restrict__ x,
                                            const float* __restrict__ values,
                                            float* __restrict__ out,
                                            int n) {
    const int base = (blockIdx.x * BLOCK + threadIdx.x) * EPT;
    if (base >= n) return;

    // Codebook: wave-uniform pointer + constant offsets -> scalar loads.
    float v[NVALS];
#pragma unroll
    for (int j = 0; j < NVALS; ++j) v[j] = values[j];

    const v4f* xp = reinterpret_cast<const v4f*>(x + base);
    v4f xv0 = __builtin_nontemporal_load(xp);
    v4f xv1 = __builtin_nontemporal_load(xp + 1);

    float xs[EPT] = {xv0.x, xv0.y, xv0.z, xv0.w,
                     xv1.x, xv1.y, xv1.z, xv1.w};

    float q[EPT];
    float idxf[EPT];
#pragma unroll
    for (int e = 0; e < EPT; ++e) {
        // Exact replication of jnp.argmin(|x - values|): first minimum wins
        // (strict <), matching the reference tie-break bit-for-bit.
        float best = fabsf(xs[e] - v[0]);
        int bi = 0;
#pragma unroll
        for (int j = 1; j < NVALS; ++j) {
            const float d = fabsf(xs[e] - v[j]);
            if (d < best) { best = d; bi = j; }
        }
        q[e] = v[bi];
        idxf[e] = (float)bi;
    }

    const size_t nn = (size_t)n;
    float* o_x   = out + base;
    float* o_q   = out + nn + base;
    float* o_zh  = out + 2 * nn + base;
    float* o_idx = out + 3 * nn + base;

    const v4f q0 = {q[0], q[1], q[2], q[3]};
    const v4f q1 = {q[4], q[5], q[6], q[7]};
    const v4f i0 = {idxf[0], idxf[1], idxf[2], idxf[3]};
    const v4f i1 = {idxf[4], idxf[5], idxf[6], idxf[7]};

    __builtin_nontemporal_store(xv0, reinterpret_cast<v4f*>(o_x));
    __builtin_nontemporal_store(xv1, reinterpret_cast<v4f*>(o_x) + 1);
    __builtin_nontemporal_store(q0, reinterpret_cast<v4f*>(o_q));
    __builtin_nontemporal_store(q1, reinterpret_cast<v4f*>(o_q) + 1);
    __builtin_nontemporal_store(q0, reinterpret_cast<v4f*>(o_zh));
    __builtin_nontemporal_store(q1, reinterpret_cast<v4f*>(o_zh) + 1);
    __builtin_nontemporal_store(i0, reinterpret_cast<v4f*>(o_idx));
    __builtin_nontemporal_store(i1, reinterpret_cast<v4f*>(o_idx) + 1);
}

extern "C" void kernel_launch(void* const* d_in, const int* in_sizes, int n_in,
                              void* d_out, int out_size, void* d_ws, size_t ws_size,
                              hipStream_t stream) {
    const float* x      = (const float*)d_in[0];
    const float* values = (const float*)d_in[1];
    float* out          = (float*)d_out;
    const int n = in_sizes[0];  // 16,777,216

    const int elems_per_block = BLOCK * EPT;  // 2048
    const int grid = (n + elems_per_block - 1) / elems_per_block;  // 8192

    GlobalQuantizedLatent_87900800680047_kernel<<<grid, BLOCK, 0, stream>>>(
        x, values, out, n);
}

// Round 4
// 322.527 us; speedup vs baseline: 1.1168x; 1.1168x over previous
//
#include <hip/hip_runtime.h>

// GlobalQuantizedLatent: per-element nearest-codebook quantization.
// N = 16,777,216 f32, V = 16 codebook entries (linspace(-0.5, 0.5, 16)).
// Outputs (concatenated flat, all read back as f32 by the harness):
//   [0,   N) : x            (copy of input)
//   [N,  2N) : quantized    (values[argmin |x - values|])
//   [2N, 3N) : z_hat        (== quantized numerically in forward)
//   [3N, 4N) : indices      (argmin index, stored as float)
//
// R3 post-mortem: non-temporal stores REGRESSED +47 us. The 256 MiB output
// fits exactly in the 256 MiB LLC; with plain stores the next iteration's
// 0xAA poison overwrites dirty lines before writeback (HBM writes elided).
// nt stores forced 256 MiB to HBM every iteration (+44 us at ~6 TB/s).
// => plain cached stores are structurally correct here. R4: plain stores,
// EPT=8 (single-variable test of the other R3 change).
//
// NOTE: the argmin MUST be the exact first-wins distance-compare loop.
// A closed-form round((x+0.5)*15) can disagree with the f32 distance
// comparison for x within ~1 ulp of codebook midpoints, giving index
// error 1.0 > the 0.3 threshold.

#define BLOCK 256
#define NVALS 16
#define EPT 8  // elements per thread

typedef float v4f __attribute__((ext_vector_type(4)));

__global__ __launch_bounds__(BLOCK) void
GlobalQuantizedLatent_87900800680047_kernel(const float* __restrict__ x,
                                            const float* __restrict__ values,
                                            float* __restrict__ out,
                                            int n) {
    const int base = (blockIdx.x * BLOCK + threadIdx.x) * EPT;
    if (base >= n) return;

    // Codebook: wave-uniform pointer + constant offsets -> scalar loads.
    float v[NVALS];
#pragma unroll
    for (int j = 0; j < NVALS; ++j) v[j] = values[j];

    const v4f* xp = reinterpret_cast<const v4f*>(x + base);
    const v4f xv0 = xp[0];
    const v4f xv1 = xp[1];

    const float xs[EPT] = {xv0.x, xv0.y, xv0.z, xv0.w,
                           xv1.x, xv1.y, xv1.z, xv1.w};

    float q[EPT];
    float idxf[EPT];
#pragma unroll
    for (int e = 0; e < EPT; ++e) {
        // Exact replication of jnp.argmin(|x - values|): first minimum wins
        // (strict <), matching the reference tie-break bit-for-bit.
        float best = fabsf(xs[e] - v[0]);
        int bi = 0;
#pragma unroll
        for (int j = 1; j < NVALS; ++j) {
            const float d = fabsf(xs[e] - v[j]);
            if (d < best) { best = d; bi = j; }
        }
        q[e] = v[bi];
        idxf[e] = (float)bi;
    }

    const size_t nn = (size_t)n;
    float* o_x   = out + base;
    float* o_q   = out + nn + base;
    float* o_zh  = out + 2 * nn + base;
    float* o_idx = out + 3 * nn + base;

    const v4f q0 = {q[0], q[1], q[2], q[3]};
    const v4f q1 = {q[4], q[5], q[6], q[7]};
    const v4f i0 = {idxf[0], idxf[1], idxf[2], idxf[3]};
    const v4f i1 = {idxf[4], idxf[5], idxf[6], idxf[7]};

    reinterpret_cast<v4f*>(o_x)[0]   = xv0;
    reinterpret_cast<v4f*>(o_x)[1]   = xv1;
    reinterpret_cast<v4f*>(o_q)[0]   = q0;
    reinterpret_cast<v4f*>(o_q)[1]   = q1;
    reinterpret_cast<v4f*>(o_zh)[0]  = q0;
    reinterpret_cast<v4f*>(o_zh)[1]  = q1;
    reinterpret_cast<v4f*>(o_idx)[0] = i0;
    reinterpret_cast<v4f*>(o_idx)[1] = i1;
}

extern "C" void kernel_launch(void* const* d_in, const int* in_sizes, int n_in,
                              void* d_out, int out_size, void* d_ws, size_t ws_size,
                              hipStream_t stream) {
    const float* x      = (const float*)d_in[0];
    const float* values = (const float*)d_in[1];
    float* out          = (float*)d_out;
    const int n = in_sizes[0];  // 16,777,216

    const int elems_per_block = BLOCK * EPT;  // 2048
    const int grid = (n + elems_per_block - 1) / elems_per_block;  // 8192

    GlobalQuantizedLatent_87900800680047_kernel<<<grid, BLOCK, 0, stream>>>(
        x, values, out, n);
}

// Round 5
// 314.412 us; speedup vs baseline: 1.1456x; 1.0258x over previous
//
#include <hip/hip_runtime.h>

// GlobalQuantizedLatent: per-element nearest-codebook quantization.
// N = 16,777,216 f32, V = 16 codebook entries (linspace(-0.5, 0.5, 16)).
// Outputs (concatenated flat, all read back as f32 by the harness):
//   [0,   N) : x            (copy of input)
//   [N,  2N) : quantized    (values[argmin |x - values|])
//   [2N, 3N) : z_hat        (== quantized numerically in forward)
//   [3N, 4N) : indices      (argmin index, stored as float)
//
// Session findings (R1-R4):
//  - R3: non-temporal stores REGRESSED +47 us. The 256 MiB output fits in
//    the 256 MiB LLC; with plain stores the next iteration's poison fill
//    overwrites dirty lines before writeback (HBM writes elided). nt
//    forced 256 MiB to HBM every iteration. Keep PLAIN cached stores.
//  - R4: EPT=8 neutral-to-slightly-negative vs EPT=4 (kernel is
//    memory-bound; VALU ~24% busy at roofline speed, so shaving address
//    math buys nothing). Keep EPT=4.
//  - Reported dur_us is dominated by harness poison fill (~167 us, 1 GiB
//    at 6.4 TB/s) + input restore; our dispatch is <165 us (never in
//    top-5) vs a ~53 us HBM-roofline for 64 MiB read + 256 MiB write.
//
// NOTE: the argmin MUST be the exact first-wins distance-compare loop.
// A closed-form round((x+0.5)*15) can disagree with the f32 distance
// comparison for x within ~1 ulp of codebook midpoints, giving index
// error 1.0 > the 0.3 threshold.

#define BLOCK 256
#define NVALS 16

typedef float v4f __attribute__((ext_vector_type(4)));

__global__ __launch_bounds__(BLOCK) void
GlobalQuantizedLatent_87900800680047_kernel(const float* __restrict__ x,
                                            const float* __restrict__ values,
                                            float* __restrict__ out,
                                            int n) {
    const int i4 = (blockIdx.x * BLOCK + threadIdx.x) * 4;
    if (i4 >= n) return;

    // Codebook: wave-uniform pointer + constant offsets -> scalar loads.
    float v[NVALS];
#pragma unroll
    for (int j = 0; j < NVALS; ++j) v[j] = values[j];

    const v4f xv = *reinterpret_cast<const v4f*>(x + i4);
    const float xs[4] = {xv.x, xv.y, xv.z, xv.w};

    float q[4];
    float idxf[4];
#pragma unroll
    for (int e = 0; e < 4; ++e) {
        // Exact replication of jnp.argmin(|x - values|): first minimum wins
        // (strict <), matching the reference tie-break bit-for-bit.
        float best = fabsf(xs[e] - v[0]);
        int bi = 0;
#pragma unroll
        for (int j = 1; j < NVALS; ++j) {
            const float d = fabsf(xs[e] - v[j]);
            if (d < best) { best = d; bi = j; }
        }
        q[e] = v[bi];
        idxf[e] = (float)bi;
    }

    const size_t nn = (size_t)n;
    const v4f qv = {q[0], q[1], q[2], q[3]};
    const v4f iv = {idxf[0], idxf[1], idxf[2], idxf[3]};

    *reinterpret_cast<v4f*>(out + i4)          = xv;
    *reinterpret_cast<v4f*>(out + nn + i4)     = qv;
    *reinterpret_cast<v4f*>(out + 2 * nn + i4) = qv;
    *reinterpret_cast<v4f*>(out + 3 * nn + i4) = iv;
}

extern "C" void kernel_launch(void* const* d_in, const int* in_sizes, int n_in,
                              void* d_out, int out_size, void* d_ws, size_t ws_size,
                              hipStream_t stream) {
    const float* x      = (const float*)d_in[0];
    const float* values = (const float*)d_in[1];
    float* out          = (float*)d_out;
    const int n = in_sizes[0];  // 16,777,216

    const int elems_per_block = BLOCK * 4;
    const int grid = (n + elems_per_block - 1) / elems_per_block;  // 16384

    GlobalQuantizedLatent_87900800680047_kernel<<<grid, BLOCK, 0, stream>>>(
        x, values, out, n);
}